// Round 1
// 561.607 us; speedup vs baseline: 1.5459x; 1.5459x over previous
//
#include <hip/hip_runtime.h>
#include <hip/hip_bf16.h>

#define ROWS 256
#define COLS 256
#define BATCH 16
#define FDIM 64
#define NPIX (ROWS * COLS)      // 65536
#define MTOT (BATCH * NPIX)     // 1048576

// K1 reduction geometry
#define NB1 1024                        // K1 grid size (blocks)
#define K1_ITERS ((MTOT / 16) / (NB1 * 4))   // 16 tiles per wave

typedef __attribute__((ext_vector_type(8))) short short8;
typedef __attribute__((ext_vector_type(4))) float floatx4;

__device__ __forceinline__ unsigned short f2bf(float f) {
    union { float f; unsigned int i; } v;
    v.f = f;
    unsigned int r = v.i + 0x7FFFu + ((v.i >> 16) & 1u);  // RNE
    return (unsigned short)(r >> 16);
}
__device__ __forceinline__ float bf2f(unsigned short u) {
    union { unsigned int i; float f; } v;
    v.i = ((unsigned int)u) << 16;
    return v.f;
}
__device__ __forceinline__ short8 pack8(float4 x, float4 y) {
    short8 o;
    o[0] = (short)f2bf(x.x); o[1] = (short)f2bf(x.y);
    o[2] = (short)f2bf(x.z); o[3] = (short)f2bf(x.w);
    o[4] = (short)f2bf(y.x); o[5] = (short)f2bf(y.y);
    o[6] = (short)f2bf(y.z); o[7] = (short)f2bf(y.w);
    return o;
}
__device__ __forceinline__ float dinv(int r, int c) {
    int rv = 3 - (r == 0) - (r == ROWS - 1);
    int cv = 3 - (c == 0) - (c == COLS - 1);
    return rsqrtf((float)(rv * cv) + 1e-5f);
}

// ---------------------------------------------------------------------------
// K1: per-feature sum / sumsq of Ht = H @ W (bf16 MFMA, fp32 acc).
// Two-level reduction: wave shuffle -> block LDS -> ONE partial store per
// block (no global atomics). Atomic path kept as fallback for tiny ws.
// A layout: A[m=lane&15][k=quad*8+j]; B layout: B[k=quad*8+j][n=lane&15];
// C/D: col=lane&15, row=quad*4+reg
// ---------------------------------------------------------------------------
__global__ __launch_bounds__(256) void k1_stats(
    const float* __restrict__ H,        // [MTOT,64] fp32
    const float* __restrict__ W,        // [64,64]  fp32 row-major [in][out]
    float* __restrict__ partials,       // [128][NB1] feature-major, or nullptr
    float* __restrict__ stats)          // [128] fp32 (atomic fallback)
{
    const int tid  = threadIdx.x;
    const int lane = tid & 63;
    const int wid  = tid >> 6;
    const int gw   = blockIdx.x * 4 + wid;   // 0..NB1*4-1
    const int n    = lane & 15;
    const int q    = lane >> 4;

    __shared__ float red[4][128];

    short8 bfrag[2][4];
    for (int kt = 0; kt < 2; ++kt)
        for (int nt = 0; nt < 4; ++nt)
            for (int j = 0; j < 8; ++j)
                bfrag[kt][nt][j] = (short)f2bf(W[(kt * 32 + q * 8 + j) * FDIM + nt * 16 + n]);

    float s[4]  = {0.f, 0.f, 0.f, 0.f};
    float s2[4] = {0.f, 0.f, 0.f, 0.f};

    #pragma unroll 2
    for (int it = 0; it < K1_ITERS; ++it) {
        const int t = gw + it * (NB1 * 4);
        const float4* ap = (const float4*)(H + ((size_t)t * 16 + n) * FDIM + q * 8);
        short8 a0 = pack8(ap[0], ap[1]);   // k = q*8 .. q*8+7
        short8 a1 = pack8(ap[8], ap[9]);   // k = 32 + q*8 ..

        floatx4 acc[4] = {};
        for (int nt = 0; nt < 4; ++nt) {
            acc[nt] = __builtin_amdgcn_mfma_f32_16x16x32_bf16(a0, bfrag[0][nt], acc[nt], 0, 0, 0);
            acc[nt] = __builtin_amdgcn_mfma_f32_16x16x32_bf16(a1, bfrag[1][nt], acc[nt], 0, 0, 0);
        }
        for (int nt = 0; nt < 4; ++nt)
            for (int r = 0; r < 4; ++r) {
                float v = acc[nt][r];
                s[nt] += v;
                s2[nt] = fmaf(v, v, s2[nt]);
            }
    }

    // wave-level reduce over the 4 row-quads (xor 16, 32)
    for (int nt = 0; nt < 4; ++nt) {
        float a = s[nt], b = s2[nt];
        a += __shfl_xor(a, 16); b += __shfl_xor(b, 16);
        a += __shfl_xor(a, 32); b += __shfl_xor(b, 32);
        if (q == 0) {
            red[wid][nt * 16 + n]      = a;
            red[wid][64 + nt * 16 + n] = b;
        }
    }
    __syncthreads();

    // block-level reduce over the 4 waves; one store (or one atomic) per block
    if (tid < 128) {
        float tot = red[0][tid] + red[1][tid] + red[2][tid] + red[3][tid];
        if (partials) partials[(size_t)tid * NB1 + blockIdx.x] = tot;
        else          atomicAdd(&stats[tid], tot);
    }
}

// ---------------------------------------------------------------------------
// K2 (partials path): reduce [128][NB1] partials, fold BN into affine:
// a = gamma*rsqrt(var+eps), b = beta - mean*a.  Block f handles feature f
// (sum row f, sumsq row f+64).
// ---------------------------------------------------------------------------
__global__ __launch_bounds__(256) void k2_reduce(
    const float* __restrict__ partials,
    const float* __restrict__ gamma,
    const float* __restrict__ beta,
    float* __restrict__ ab)
{
    const int f   = blockIdx.x;          // 0..63
    const int tid = threadIdx.x;         // 0..255
    const float4* p0 = (const float4*)(partials + (size_t)f * NB1);
    const float4* p1 = (const float4*)(partials + (size_t)(f + 64) * NB1);
    float4 v0 = p0[tid];                 // 256 threads x 4 floats = NB1
    float4 v1 = p1[tid];
    float s0 = v0.x + v0.y + v0.z + v0.w;
    float s1 = v1.x + v1.y + v1.z + v1.w;
    for (int off = 1; off < 64; off <<= 1) {
        s0 += __shfl_xor(s0, off);
        s1 += __shfl_xor(s1, off);
    }
    __shared__ float r0[4], r1[4];
    const int wid = tid >> 6, lane = tid & 63;
    if (lane == 0) { r0[wid] = s0; r1[wid] = s1; }
    __syncthreads();
    if (tid == 0) {
        float S = r0[0] + r0[1] + r0[2] + r0[3];
        float Q = r1[0] + r1[1] + r1[2] + r1[3];
        const float inv_m = 1.0f / (float)MTOT;
        float mean = S * inv_m;
        float var  = Q * inv_m - mean * mean;
        float a = gamma[f] * rsqrtf(var + 1e-5f);
        ab[f]      = a;
        ab[64 + f] = beta[f] - mean * a;
    }
}

// ---------------------------------------------------------------------------
// K2 (atomic fallback path): fold BN into per-feature affine from stats.
// ---------------------------------------------------------------------------
__global__ void k2_finalize(const float* __restrict__ stats,
                            const float* __restrict__ gamma,
                            const float* __restrict__ beta,
                            float* __restrict__ ab)
{
    int t = threadIdx.x;
    if (t < 64) {
        const float inv_m = 1.0f / (float)MTOT;
        float mean = stats[t] * inv_m;
        float var  = stats[64 + t] * inv_m - mean * mean;
        float a = gamma[t] * rsqrtf(var + 1e-5f);
        ab[t]      = a;
        ab[64 + t] = beta[t] - mean * a;
    }
}

// ---------------------------------------------------------------------------
// K3: per (batch, 8x32 output tile): recompute Ht = H@W for the 10x34 halo
// via MFMA, apply affine+relu+*d_j into LDS (bf16), then 9-point stencil,
// *d_i, write fp32 out.   (unchanged this round — isolate the K1 delta)
// ---------------------------------------------------------------------------
#define TH 8
#define TW 32
#define IH (TH + 2)
#define IW (TW + 2)
#define NHALO (IH * IW)        // 340
#define NCHUNK 22              // ceil(340/16)

__global__ __launch_bounds__(256) void k3_fused(
    const float* __restrict__ H,
    const float* __restrict__ W,
    const float* __restrict__ ab,
    float* __restrict__ out)
{
    __shared__ unsigned short P[NHALO * FDIM];   // 43,520 B
    __shared__ float abv[2 * FDIM];

    const int tid  = threadIdx.x;
    const int lane = tid & 63;
    const int wid  = tid >> 6;
    const int n    = lane & 15;
    const int q    = lane >> 4;

    int bid = blockIdx.x;
    const int ct = bid & 7;   bid >>= 3;   // 8 col tiles
    const int rt = bid & 31;  bid >>= 5;   // 32 row tiles
    const int bb = bid;                    // batch
    const int r0 = rt * TH, c0 = ct * TW;
    const size_t base = (size_t)bb * NPIX * FDIM;

    if (tid < 128) abv[tid] = ab[tid];

    short8 bfrag[2][4];
    for (int kt = 0; kt < 2; ++kt)
        for (int nt = 0; nt < 4; ++nt)
            for (int j = 0; j < 8; ++j)
                bfrag[kt][nt][j] = (short)f2bf(W[(kt * 32 + q * 8 + j) * FDIM + nt * 16 + n]);
    __syncthreads();

    // Phase A: GEMM -> affine -> relu -> *d_j -> LDS (bf16)
    for (int ch = wid; ch < NCHUNK; ch += 4) {
        int p = ch * 16 + n;
        short8 a0 = {}; short8 a1 = {};
        if (p < NHALO) {
            int ri = p / IW, ci = p - ri * IW;
            int r = r0 - 1 + ri, c = c0 - 1 + ci;
            if ((unsigned)r < ROWS && (unsigned)c < COLS) {
                const float4* apx = (const float4*)(H + base + (size_t)(r * COLS + c) * FDIM + q * 8);
                a0 = pack8(apx[0], apx[1]);
                a1 = pack8(apx[8], apx[9]);
            }
        }
        floatx4 acc[4] = {};
        for (int nt = 0; nt < 4; ++nt) {
            acc[nt] = __builtin_amdgcn_mfma_f32_16x16x32_bf16(a0, bfrag[0][nt], acc[nt], 0, 0, 0);
            acc[nt] = __builtin_amdgcn_mfma_f32_16x16x32_bf16(a1, bfrag[1][nt], acc[nt], 0, 0, 0);
        }
        for (int nt = 0; nt < 4; ++nt) {
            float av = abv[nt * 16 + n], bv = abv[64 + nt * 16 + n];
            for (int rr = 0; rr < 4; ++rr) {
                int pp = ch * 16 + q * 4 + rr;
                if (pp < NHALO) {
                    int ri = pp / IW, ci = pp - ri * IW;
                    int r = r0 - 1 + ri, c = c0 - 1 + ci;
                    float d = 0.f;
                    if ((unsigned)r < ROWS && (unsigned)c < COLS) d = dinv(r, c);
                    float y = fmaxf(fmaf(acc[nt][rr], av, bv), 0.f) * d;
                    P[pp * FDIM + nt * 16 + n] = f2bf(y);
                }
            }
        }
    }
    __syncthreads();

    // Phase B: 9-point stencil from LDS, * d_i, fp32 store
    const int fg = tid & 7;
    for (int po = tid >> 3; po < TH * TW; po += 32) {
        int orr = po >> 5;      // / TW
        int oc  = po & 31;      // % TW
        float acc8[8] = {0.f, 0.f, 0.f, 0.f, 0.f, 0.f, 0.f, 0.f};
        for (int dr = 0; dr < 3; ++dr)
            for (int dc = 0; dc < 3; ++dc) {
                const short8 v = *(const short8*)&P[((orr + dr) * IW + (oc + dc)) * FDIM + fg * 8];
                for (int j = 0; j < 8; ++j)
                    acc8[j] += bf2f((unsigned short)v[j]);
            }
        int r = r0 + orr, c = c0 + oc;
        float d = dinv(r, c);
        float4 o0, o1;
        o0.x = acc8[0] * d; o0.y = acc8[1] * d; o0.z = acc8[2] * d; o0.w = acc8[3] * d;
        o1.x = acc8[4] * d; o1.y = acc8[5] * d; o1.z = acc8[6] * d; o1.w = acc8[7] * d;
        float4* op = (float4*)(out + base + (size_t)(r * COLS + c) * FDIM + fg * 8);
        op[0] = o0; op[1] = o1;
    }
}

extern "C" void kernel_launch(void* const* d_in, const int* in_sizes, int n_in,
                              void* d_out, int out_size, void* d_ws, size_t ws_size,
                              hipStream_t stream) {
    const float* H     = (const float*)d_in[0];
    const float* W     = (const float*)d_in[1];
    const float* gamma = (const float*)d_in[2];
    const float* beta  = (const float*)d_in[3];
    float* out = (float*)d_out;

    float* ab       = (float*)d_ws;          // [128]
    float* stats    = ab + 128;              // [128]  (atomic fallback)
    float* partials = stats + 128;           // [128][NB1] (partials path)

    const size_t need = (size_t)(256 + 128 * NB1) * sizeof(float);
    if (ws_size >= need) {
        // no-atomics path: per-block partial sums, reduced by k2_reduce
        k1_stats<<<NB1, 256, 0, stream>>>(H, W, partials, nullptr);
        k2_reduce<<<64, 256, 0, stream>>>(partials, gamma, beta, ab);
    } else {
        // fallback: per-block atomics (16x fewer than before)
        hipMemsetAsync(stats, 0, 128 * sizeof(float), stream);
        k1_stats<<<NB1, 256, 0, stream>>>(H, W, nullptr, stats);
        k2_finalize<<<1, 64, 0, stream>>>(stats, gamma, beta, ab);
    }
    k3_fused<<<BATCH * 32 * 8, 256, 0, stream>>>(H, W, ab, out);
}

// Round 2
// 527.056 us; speedup vs baseline: 1.6472x; 1.0656x over previous
//
#include <hip/hip_runtime.h>
#include <hip/hip_bf16.h>

#define ROWS 256
#define COLS 256
#define BATCH 16
#define FDIM 64
#define NPIX (ROWS * COLS)      // 65536
#define MTOT (BATCH * NPIX)     // 1048576

// K1 reduction geometry
#define NB1 1024                        // K1 grid size (blocks)
#define K1_ITERS ((MTOT / 16) / (NB1 * 4))   // 16 tiles per wave

typedef __attribute__((ext_vector_type(8))) short short8;
typedef __attribute__((ext_vector_type(4))) float floatx4;

__device__ __forceinline__ unsigned short f2bf(float f) {
    union { float f; unsigned int i; } v;
    v.f = f;
    unsigned int r = v.i + 0x7FFFu + ((v.i >> 16) & 1u);  // RNE
    return (unsigned short)(r >> 16);
}
__device__ __forceinline__ float bf2f(unsigned short u) {
    union { unsigned int i; float f; } v;
    v.i = ((unsigned int)u) << 16;
    return v.f;
}
__device__ __forceinline__ short8 pack8(float4 x, float4 y) {
    short8 o;
    o[0] = (short)f2bf(x.x); o[1] = (short)f2bf(x.y);
    o[2] = (short)f2bf(x.z); o[3] = (short)f2bf(x.w);
    o[4] = (short)f2bf(y.x); o[5] = (short)f2bf(y.y);
    o[6] = (short)f2bf(y.z); o[7] = (short)f2bf(y.w);
    return o;
}
__device__ __forceinline__ float dinv(int r, int c) {
    int rv = 3 - (r == 0) - (r == ROWS - 1);
    int cv = 3 - (c == 0) - (c == COLS - 1);
    return rsqrtf((float)(rv * cv) + 1e-5f);
}

// ---------------------------------------------------------------------------
// K1: per-feature sum / sumsq of Ht = H @ W (bf16 MFMA, fp32 acc).
// Two-level reduction: wave shuffle -> block LDS -> one partial store per
// block (no global atomics).  NEW: also stores the packed bf16 H rows to the
// workspace (row-major [MTOT][64] bf16) so K3 can skip fp32 loads + pack8.
// A layout: A[m=lane&15][k=quad*8+j]; B layout: B[k=quad*8+j][n=lane&15];
// C/D: col=lane&15, row=quad*4+reg
// ---------------------------------------------------------------------------
__global__ __launch_bounds__(256) void k1_stats(
    const float* __restrict__ H,        // [MTOT,64] fp32
    const float* __restrict__ W,        // [64,64]  fp32 row-major [in][out]
    float* __restrict__ partials,       // [128][NB1] feature-major, or nullptr
    float* __restrict__ stats,          // [128] fp32 (atomic fallback)
    unsigned short* __restrict__ hbf)   // [MTOT][64] bf16 out, or nullptr
{
    const int tid  = threadIdx.x;
    const int lane = tid & 63;
    const int wid  = tid >> 6;
    const int gw   = blockIdx.x * 4 + wid;   // 0..NB1*4-1
    const int n    = lane & 15;
    const int q    = lane >> 4;

    __shared__ float red[4][128];

    short8 bfrag[2][4];
    for (int kt = 0; kt < 2; ++kt)
        for (int nt = 0; nt < 4; ++nt)
            for (int j = 0; j < 8; ++j)
                bfrag[kt][nt][j] = (short)f2bf(W[(kt * 32 + q * 8 + j) * FDIM + nt * 16 + n]);

    float s[4]  = {0.f, 0.f, 0.f, 0.f};
    float s2[4] = {0.f, 0.f, 0.f, 0.f};

    #pragma unroll 2
    for (int it = 0; it < K1_ITERS; ++it) {
        const int t = gw + it * (NB1 * 4);
        const float4* ap = (const float4*)(H + ((size_t)t * 16 + n) * FDIM + q * 8);
        short8 a0 = pack8(ap[0], ap[1]);   // k = q*8 .. q*8+7
        short8 a1 = pack8(ap[8], ap[9]);   // k = 32 + q*8 ..

        if (hbf) {
            short8* sp = (short8*)(hbf + ((size_t)t * 16 + n) * FDIM);
            sp[q]     = a0;                // cols q*8 .. q*8+7
            sp[q + 4] = a1;                // cols 32+q*8 ..
        }

        floatx4 acc[4] = {};
        for (int nt = 0; nt < 4; ++nt) {
            acc[nt] = __builtin_amdgcn_mfma_f32_16x16x32_bf16(a0, bfrag[0][nt], acc[nt], 0, 0, 0);
            acc[nt] = __builtin_amdgcn_mfma_f32_16x16x32_bf16(a1, bfrag[1][nt], acc[nt], 0, 0, 0);
        }
        for (int nt = 0; nt < 4; ++nt)
            for (int r = 0; r < 4; ++r) {
                float v = acc[nt][r];
                s[nt] += v;
                s2[nt] = fmaf(v, v, s2[nt]);
            }
    }

    // wave-level reduce over the 4 row-quads (xor 16, 32)
    for (int nt = 0; nt < 4; ++nt) {
        float a = s[nt], b = s2[nt];
        a += __shfl_xor(a, 16); b += __shfl_xor(b, 16);
        a += __shfl_xor(a, 32); b += __shfl_xor(b, 32);
        if (q == 0) {
            red[wid][nt * 16 + n]      = a;
            red[wid][64 + nt * 16 + n] = b;
        }
    }
    __syncthreads();

    // block-level reduce over the 4 waves; one store (or one atomic) per block
    if (tid < 128) {
        float tot = red[0][tid] + red[1][tid] + red[2][tid] + red[3][tid];
        if (partials) partials[(size_t)tid * NB1 + blockIdx.x] = tot;
        else          atomicAdd(&stats[tid], tot);
    }
}

// ---------------------------------------------------------------------------
// K2 (partials path): reduce [128][NB1] partials, fold BN into affine:
// a = gamma*rsqrt(var+eps), b = beta - mean*a.
// ---------------------------------------------------------------------------
__global__ __launch_bounds__(256) void k2_reduce(
    const float* __restrict__ partials,
    const float* __restrict__ gamma,
    const float* __restrict__ beta,
    float* __restrict__ ab)
{
    const int f   = blockIdx.x;          // 0..63
    const int tid = threadIdx.x;         // 0..255
    const float4* p0 = (const float4*)(partials + (size_t)f * NB1);
    const float4* p1 = (const float4*)(partials + (size_t)(f + 64) * NB1);
    float4 v0 = p0[tid];                 // 256 threads x 4 floats = NB1
    float4 v1 = p1[tid];
    float s0 = v0.x + v0.y + v0.z + v0.w;
    float s1 = v1.x + v1.y + v1.z + v1.w;
    for (int off = 1; off < 64; off <<= 1) {
        s0 += __shfl_xor(s0, off);
        s1 += __shfl_xor(s1, off);
    }
    __shared__ float r0[4], r1[4];
    const int wid = tid >> 6, lane = tid & 63;
    if (lane == 0) { r0[wid] = s0; r1[wid] = s1; }
    __syncthreads();
    if (tid == 0) {
        float S = r0[0] + r0[1] + r0[2] + r0[3];
        float Q = r1[0] + r1[1] + r1[2] + r1[3];
        const float inv_m = 1.0f / (float)MTOT;
        float mean = S * inv_m;
        float var  = Q * inv_m - mean * mean;
        float a = gamma[f] * rsqrtf(var + 1e-5f);
        ab[f]      = a;
        ab[64 + f] = beta[f] - mean * a;
    }
}

// ---------------------------------------------------------------------------
// K2 (atomic fallback path)
// ---------------------------------------------------------------------------
__global__ void k2_finalize(const float* __restrict__ stats,
                            const float* __restrict__ gamma,
                            const float* __restrict__ beta,
                            float* __restrict__ ab)
{
    int t = threadIdx.x;
    if (t < 64) {
        const float inv_m = 1.0f / (float)MTOT;
        float mean = stats[t] * inv_m;
        float var  = stats[64 + t] * inv_m - mean * mean;
        float a = gamma[t] * rsqrtf(var + 1e-5f);
        ab[t]      = a;
        ab[64 + t] = beta[t] - mean * a;
    }
}

// ---------------------------------------------------------------------------
// K3: per (batch, 8x32 output tile): GEMM (bf16 frags direct from workspace)
// -> affine+relu+*d_j -> bf16 LDS -> SEPARABLE 3x3 stencil -> *d_i -> fp32.
// VALU diet vs prev round: LDS tables (goff, d_j) kill per-element division /
// dinv / bounds checks; bf16-H workspace kills pack8; rolling column sums
// turn 9-pt gather (72 cvt + 72 add / px) into 3+3 (24 cvt + 40 flop / px).
// ---------------------------------------------------------------------------
#define TH 8
#define TW 32
#define IH (TH + 2)
#define IW (TW + 2)
#define NHALO (IH * IW)        // 340
#define NHPAD 352              // padded to chunk multiple (22*16)
#define NCHUNK 22              // ceil(340/16)

__global__ __launch_bounds__(256) void k3_fused(
    const float* __restrict__ H,              // fp32 fallback input
    const unsigned short* __restrict__ hbf,   // bf16 H (or nullptr)
    const float* __restrict__ W,
    const float* __restrict__ ab,
    float* __restrict__ out)
{
    __shared__ unsigned short P[NHPAD * FDIM];   // 45,056 B (incl pad rows)
    __shared__ float abv[2 * FDIM];
    __shared__ float djt[NHPAD];                 // d_j per halo pixel (0 = OOB)
    __shared__ int   gofft[NHPAD];               // r*COLS+c per halo pixel (-1 = OOB)

    const int tid  = threadIdx.x;
    const int lane = tid & 63;
    const int wid  = tid >> 6;
    const int n    = lane & 15;
    const int q    = lane >> 4;

    int bid = blockIdx.x;
    const int ct = bid & 7;   bid >>= 3;   // 8 col tiles
    const int rt = bid & 31;  bid >>= 5;   // 32 row tiles
    const int bb = bid;                    // batch
    const int r0 = rt * TH, c0 = ct * TW;
    const size_t base = (size_t)bb * NPIX * FDIM;   // element offset (fp32/bf16/out)

    if (tid < 128) abv[tid] = ab[tid];
    for (int p = tid; p < NHPAD; p += 256) {
        int ri = p / IW, ci = p - ri * IW;
        int r = r0 - 1 + ri, c = c0 - 1 + ci;
        bool ok = (p < NHALO) && ((unsigned)r < ROWS) && ((unsigned)c < COLS);
        djt[p]   = ok ? dinv(r, c) : 0.f;
        gofft[p] = ok ? (r * COLS + c) : -1;
    }

    short8 bfrag[2][4];
    for (int kt = 0; kt < 2; ++kt)
        for (int nt = 0; nt < 4; ++nt)
            for (int j = 0; j < 8; ++j)
                bfrag[kt][nt][j] = (short)f2bf(W[(kt * 32 + q * 8 + j) * FDIM + nt * 16 + n]);
    __syncthreads();

    float av[4], bv[4];
    #pragma unroll
    for (int nt = 0; nt < 4; ++nt) {
        av[nt] = abv[nt * 16 + n];
        bv[nt] = abv[64 + nt * 16 + n];
    }

    // Phase A: GEMM -> affine -> relu -> *d_j -> LDS (bf16)
    for (int ch = wid; ch < NCHUNK; ch += 4) {
        const int p  = ch * 16 + n;
        const int go = gofft[p];
        short8 a0 = {}, a1 = {};
        if (hbf) {
            if (go >= 0) {
                const short8* ap = (const short8*)(hbf + base + (size_t)go * FDIM);
                a0 = ap[q];
                a1 = ap[q + 4];
            }
        } else {
            if (go >= 0) {
                const float4* apx = (const float4*)(H + base + (size_t)go * FDIM + q * 8);
                a0 = pack8(apx[0], apx[1]);
                a1 = pack8(apx[8], apx[9]);
            }
        }
        floatx4 acc[4] = {};
        #pragma unroll
        for (int nt = 0; nt < 4; ++nt) {
            acc[nt] = __builtin_amdgcn_mfma_f32_16x16x32_bf16(a0, bfrag[0][nt], acc[nt], 0, 0, 0);
            acc[nt] = __builtin_amdgcn_mfma_f32_16x16x32_bf16(a1, bfrag[1][nt], acc[nt], 0, 0, 0);
        }
        const int pb = ch * 16 + q * 4;
        const floatx4 dj4 = *(const floatx4*)&djt[pb];
        #pragma unroll
        for (int nt = 0; nt < 4; ++nt) {
            #pragma unroll
            for (int rr = 0; rr < 4; ++rr) {
                float y = fmaxf(fmaf(acc[nt][rr], av[nt], bv[nt]), 0.f) * dj4[rr];
                P[(pb + rr) * FDIM + nt * 16 + n] = f2bf(y);   // OOB rows: dj=0 -> 0
            }
        }
    }
    __syncthreads();

    // Phase B: separable 3x3 stencil via rolling column sums, * d_i, store
    {
        const int fg  = tid & 7;              // feature group (8 floats)
        const int ocg = (tid >> 3) & 3;       // 8-col strip
        const int orr = tid >> 5;             // output row 0..7
        const int hc0 = ocg * 8;              // first halo col of strip
        const unsigned short* Pr0 = &P[((orr + 0) * IW + hc0) * FDIM + fg * 8];
        const unsigned short* Pr1 = Pr0 + IW * FDIM;
        const unsigned short* Pr2 = Pr1 + IW * FDIM;

        float cs[3][8];
        #pragma unroll
        for (int ini = 0; ini < 2; ++ini) {
            const short8 v0 = *(const short8*)(Pr0 + ini * FDIM);
            const short8 v1 = *(const short8*)(Pr1 + ini * FDIM);
            const short8 v2 = *(const short8*)(Pr2 + ini * FDIM);
            #pragma unroll
            for (int j = 0; j < 8; ++j)
                cs[ini][j] = bf2f((unsigned short)v0[j]) + bf2f((unsigned short)v1[j])
                           + bf2f((unsigned short)v2[j]);
        }

        const int r = r0 + orr;
        float* orow = out + base + ((size_t)r * COLS + (c0 + hc0)) * FDIM + fg * 8;
        #pragma unroll
        for (int jj = 0; jj < 8; ++jj) {
            const int i0 = jj % 3, i1 = (jj + 1) % 3, i2 = (jj + 2) % 3;
            const short8 v0 = *(const short8*)(Pr0 + (jj + 2) * FDIM);
            const short8 v1 = *(const short8*)(Pr1 + (jj + 2) * FDIM);
            const short8 v2 = *(const short8*)(Pr2 + (jj + 2) * FDIM);
            #pragma unroll
            for (int j = 0; j < 8; ++j)
                cs[i2][j] = bf2f((unsigned short)v0[j]) + bf2f((unsigned short)v1[j])
                          + bf2f((unsigned short)v2[j]);
            const float d = djt[(orr + 1) * IW + hc0 + jj + 1];
            float4 o0, o1;
            o0.x = (cs[i0][0] + cs[i1][0] + cs[i2][0]) * d;
            o0.y = (cs[i0][1] + cs[i1][1] + cs[i2][1]) * d;
            o0.z = (cs[i0][2] + cs[i1][2] + cs[i2][2]) * d;
            o0.w = (cs[i0][3] + cs[i1][3] + cs[i2][3]) * d;
            o1.x = (cs[i0][4] + cs[i1][4] + cs[i2][4]) * d;
            o1.y = (cs[i0][5] + cs[i1][5] + cs[i2][5]) * d;
            o1.z = (cs[i0][6] + cs[i1][6] + cs[i2][6]) * d;
            o1.w = (cs[i0][7] + cs[i1][7] + cs[i2][7]) * d;
            float4* op = (float4*)(orow + (size_t)jj * FDIM);
            op[0] = o0; op[1] = o1;
        }
    }
}

extern "C" void kernel_launch(void* const* d_in, const int* in_sizes, int n_in,
                              void* d_out, int out_size, void* d_ws, size_t ws_size,
                              hipStream_t stream) {
    const float* H     = (const float*)d_in[0];
    const float* W     = (const float*)d_in[1];
    const float* gamma = (const float*)d_in[2];
    const float* beta  = (const float*)d_in[3];
    float* out = (float*)d_out;

    float* ab       = (float*)d_ws;          // [128]
    float* stats    = ab + 128;              // [128]  (atomic fallback)
    float* partials = stats + 128;           // [128][NB1] (partials path)
    unsigned short* hbf = (unsigned short*)(partials + (size_t)128 * NB1);

    const size_t need_part = (size_t)(256 + 128 * NB1) * sizeof(float);
    const size_t need_full = need_part + (size_t)MTOT * FDIM * sizeof(unsigned short);

    if (ws_size >= need_full) {
        // bf16-H cached in ws: K3 skips fp32 loads + pack8 entirely
        k1_stats<<<NB1, 256, 0, stream>>>(H, W, partials, nullptr, hbf);
        k2_reduce<<<64, 256, 0, stream>>>(partials, gamma, beta, ab);
        k3_fused<<<BATCH * 32 * 8, 256, 0, stream>>>(H, hbf, W, ab, out);
    } else if (ws_size >= need_part) {
        k1_stats<<<NB1, 256, 0, stream>>>(H, W, partials, nullptr, nullptr);
        k2_reduce<<<64, 256, 0, stream>>>(partials, gamma, beta, ab);
        k3_fused<<<BATCH * 32 * 8, 256, 0, stream>>>(H, nullptr, W, ab, out);
    } else {
        hipMemsetAsync(stats, 0, 128 * sizeof(float), stream);
        k1_stats<<<NB1, 256, 0, stream>>>(H, W, nullptr, stats, nullptr);
        k2_finalize<<<1, 64, 0, stream>>>(stats, gamma, beta, ab);
        k3_fused<<<BATCH * 32 * 8, 256, 0, stream>>>(H, nullptr, W, ab, out);
    }
}

// Round 3
// 524.598 us; speedup vs baseline: 1.6550x; 1.0047x over previous
//
#include <hip/hip_runtime.h>
#include <hip/hip_bf16.h>

#define ROWS 256
#define COLS 256
#define BATCH 16
#define FDIM 64
#define NPIX (ROWS * COLS)      // 65536
#define MTOT (BATCH * NPIX)     // 1048576

// K1 reduction geometry
#define NB1 1024                        // K1 grid size (blocks)
#define K1_ITERS ((MTOT / 16) / (NB1 * 4))   // 16 tiles per wave

typedef __attribute__((ext_vector_type(8))) short short8;
typedef __attribute__((ext_vector_type(4))) float floatx4;

__device__ __forceinline__ unsigned short f2bf(float f) {
    union { float f; unsigned int i; } v;
    v.f = f;
    unsigned int r = v.i + 0x7FFFu + ((v.i >> 16) & 1u);  // RNE
    return (unsigned short)(r >> 16);
}
__device__ __forceinline__ float bf2f(unsigned short u) {
    union { unsigned int i; float f; } v;
    v.i = ((unsigned int)u) << 16;
    return v.f;
}
__device__ __forceinline__ short8 pack8(float4 x, float4 y) {
    short8 o;
    o[0] = (short)f2bf(x.x); o[1] = (short)f2bf(x.y);
    o[2] = (short)f2bf(x.z); o[3] = (short)f2bf(x.w);
    o[4] = (short)f2bf(y.x); o[5] = (short)f2bf(y.y);
    o[6] = (short)f2bf(y.z); o[7] = (short)f2bf(y.w);
    return o;
}
__device__ __forceinline__ float dinv(int r, int c) {
    int rv = 3 - (r == 0) - (r == ROWS - 1);
    int cv = 3 - (c == 0) - (c == COLS - 1);
    return rsqrtf((float)(rv * cv) + 1e-5f);
}

// LDS XOR-swizzle for the P tile: rows are 128 B (64 bf16 features).
// Conflicting reader groups differ by px multiples of 8 (ocg) and 34 (orr);
// XOR-ing (px>>3)&7 into the 16B-slot index spreads them across banks.
// Applied on BOTH write and read sides (same involution).
__device__ __forceinline__ void* pswz(void* Pbase, int pix, int fb) {
    unsigned off = ((unsigned)pix << 7) + (unsigned)fb;
    off ^= (((unsigned)pix >> 3) & 7u) << 4;
    return (char*)Pbase + off;
}

// ---------------------------------------------------------------------------
// K1: per-feature sum / sumsq of Ht = H @ W (bf16 MFMA, fp32 acc).
// Two-level reduction: wave shuffle -> block LDS -> one partial store per
// block (no global atomics).  Also stores packed bf16 H rows to workspace
// (row-major [MTOT][64] bf16) so K3 skips fp32 loads + pack8.
// A layout: A[m=lane&15][k=quad*8+j]; B layout: B[k=quad*8+j][n=lane&15];
// C/D: col=lane&15, row=quad*4+reg
// ---------------------------------------------------------------------------
__global__ __launch_bounds__(256) void k1_stats(
    const float* __restrict__ H,        // [MTOT,64] fp32
    const float* __restrict__ W,        // [64,64]  fp32 row-major [in][out]
    float* __restrict__ partials,       // [128][NB1] feature-major, or nullptr
    float* __restrict__ stats,          // [128] fp32 (atomic fallback)
    unsigned short* __restrict__ hbf)   // [MTOT][64] bf16 out, or nullptr
{
    const int tid  = threadIdx.x;
    const int lane = tid & 63;
    const int wid  = tid >> 6;
    const int gw   = blockIdx.x * 4 + wid;   // 0..NB1*4-1
    const int n    = lane & 15;
    const int q    = lane >> 4;

    __shared__ float red[4][128];

    short8 bfrag[2][4];
    for (int kt = 0; kt < 2; ++kt)
        for (int nt = 0; nt < 4; ++nt)
            for (int j = 0; j < 8; ++j)
                bfrag[kt][nt][j] = (short)f2bf(W[(kt * 32 + q * 8 + j) * FDIM + nt * 16 + n]);

    float s[4]  = {0.f, 0.f, 0.f, 0.f};
    float s2[4] = {0.f, 0.f, 0.f, 0.f};

    #pragma unroll 2
    for (int it = 0; it < K1_ITERS; ++it) {
        const int t = gw + it * (NB1 * 4);
        const float4* ap = (const float4*)(H + ((size_t)t * 16 + n) * FDIM + q * 8);
        short8 a0 = pack8(ap[0], ap[1]);   // k = q*8 .. q*8+7
        short8 a1 = pack8(ap[8], ap[9]);   // k = 32 + q*8 ..

        if (hbf) {
            short8* sp = (short8*)(hbf + ((size_t)t * 16 + n) * FDIM);
            sp[q]     = a0;                // cols q*8 .. q*8+7
            sp[q + 4] = a1;                // cols 32+q*8 ..
        }

        floatx4 acc[4] = {};
        for (int nt = 0; nt < 4; ++nt) {
            acc[nt] = __builtin_amdgcn_mfma_f32_16x16x32_bf16(a0, bfrag[0][nt], acc[nt], 0, 0, 0);
            acc[nt] = __builtin_amdgcn_mfma_f32_16x16x32_bf16(a1, bfrag[1][nt], acc[nt], 0, 0, 0);
        }
        for (int nt = 0; nt < 4; ++nt)
            for (int r = 0; r < 4; ++r) {
                float v = acc[nt][r];
                s[nt] += v;
                s2[nt] = fmaf(v, v, s2[nt]);
            }
    }

    // wave-level reduce over the 4 row-quads (xor 16, 32)
    for (int nt = 0; nt < 4; ++nt) {
        float a = s[nt], b = s2[nt];
        a += __shfl_xor(a, 16); b += __shfl_xor(b, 16);
        a += __shfl_xor(a, 32); b += __shfl_xor(b, 32);
        if (q == 0) {
            red[wid][nt * 16 + n]      = a;
            red[wid][64 + nt * 16 + n] = b;
        }
    }
    __syncthreads();

    // block-level reduce over the 4 waves; one store (or one atomic) per block
    if (tid < 128) {
        float tot = red[0][tid] + red[1][tid] + red[2][tid] + red[3][tid];
        if (partials) partials[(size_t)tid * NB1 + blockIdx.x] = tot;
        else          atomicAdd(&stats[tid], tot);
    }
}

// ---------------------------------------------------------------------------
// K2 (partials path): reduce [128][NB1] partials, fold BN into affine:
// a = gamma*rsqrt(var+eps), b = beta - mean*a.
// ---------------------------------------------------------------------------
__global__ __launch_bounds__(256) void k2_reduce(
    const float* __restrict__ partials,
    const float* __restrict__ gamma,
    const float* __restrict__ beta,
    float* __restrict__ ab)
{
    const int f   = blockIdx.x;          // 0..63
    const int tid = threadIdx.x;         // 0..255
    const float4* p0 = (const float4*)(partials + (size_t)f * NB1);
    const float4* p1 = (const float4*)(partials + (size_t)(f + 64) * NB1);
    float4 v0 = p0[tid];                 // 256 threads x 4 floats = NB1
    float4 v1 = p1[tid];
    float s0 = v0.x + v0.y + v0.z + v0.w;
    float s1 = v1.x + v1.y + v1.z + v1.w;
    for (int off = 1; off < 64; off <<= 1) {
        s0 += __shfl_xor(s0, off);
        s1 += __shfl_xor(s1, off);
    }
    __shared__ float r0[4], r1[4];
    const int wid = tid >> 6, lane = tid & 63;
    if (lane == 0) { r0[wid] = s0; r1[wid] = s1; }
    __syncthreads();
    if (tid == 0) {
        float S = r0[0] + r0[1] + r0[2] + r0[3];
        float Q = r1[0] + r1[1] + r1[2] + r1[3];
        const float inv_m = 1.0f / (float)MTOT;
        float mean = S * inv_m;
        float var  = Q * inv_m - mean * mean;
        float a = gamma[f] * rsqrtf(var + 1e-5f);
        ab[f]      = a;
        ab[64 + f] = beta[f] - mean * a;
    }
}

// ---------------------------------------------------------------------------
// K2 (atomic fallback path)
// ---------------------------------------------------------------------------
__global__ void k2_finalize(const float* __restrict__ stats,
                            const float* __restrict__ gamma,
                            const float* __restrict__ beta,
                            float* __restrict__ ab)
{
    int t = threadIdx.x;
    if (t < 64) {
        const float inv_m = 1.0f / (float)MTOT;
        float mean = stats[t] * inv_m;
        float var  = stats[64 + t] * inv_m - mean * mean;
        float a = gamma[t] * rsqrtf(var + 1e-5f);
        ab[t]      = a;
        ab[64 + t] = beta[t] - mean * a;
    }
}

// ---------------------------------------------------------------------------
// K3: per (batch, 8x32 output tile): GEMM (bf16 frags direct from workspace)
// -> affine+relu+*d_j -> bf16 LDS (XOR-swizzled) -> separable 3x3 stencil
// -> *d_i -> fp32 out.
// This round: (a) MFMA B-columns remapped so lane n owns CONSECUTIVE
// features f=n*4+nt -> epilogue writes 4x ds_write_b64 instead of 16x b16;
// (b) P addresses XOR-swizzled (both sides) to kill the 8-way Phase-B read
// conflict (ocg d=8px, orr d=34px were bank-aliased) and the 4-way Phase-A
// write conflict across q.
// ---------------------------------------------------------------------------
#define TH 8
#define TW 32
#define IH (TH + 2)
#define IW (TW + 2)
#define NHALO (IH * IW)        // 340
#define NHPAD 352              // padded to chunk multiple (22*16)
#define NCHUNK 22              // ceil(340/16)

template <int USEHBF>
__global__ __launch_bounds__(256) void k3_fused(
    const float* __restrict__ H,              // fp32 fallback input
    const unsigned short* __restrict__ hbf,   // bf16 H (hot path)
    const float* __restrict__ W,
    const float* __restrict__ ab,
    float* __restrict__ out)
{
    __shared__ unsigned short P[NHPAD * FDIM];   // 45,056 B (swizzled)
    __shared__ float abv[2 * FDIM];
    __shared__ float djt[NHPAD];                 // d_j per halo pixel (0 = OOB)
    __shared__ int   gofft[NHPAD];               // r*COLS+c per halo pixel (-1 = OOB)

    const int tid  = threadIdx.x;
    const int lane = tid & 63;
    const int wid  = tid >> 6;
    const int n    = lane & 15;
    const int q    = lane >> 4;

    int bid = blockIdx.x;
    const int ct = bid & 7;   bid >>= 3;   // 8 col tiles
    const int rt = bid & 31;  bid >>= 5;   // 32 row tiles
    const int bb = bid;                    // batch
    const int r0 = rt * TH, c0 = ct * TW;
    const size_t base = (size_t)bb * NPIX * FDIM;   // element offset

    if (tid < 128) abv[tid] = ab[tid];
    for (int p = tid; p < NHPAD; p += 256) {
        int ri = p / IW, ci = p - ri * IW;
        int r = r0 - 1 + ri, c = c0 - 1 + ci;
        bool ok = (p < NHALO) && ((unsigned)r < ROWS) && ((unsigned)c < COLS);
        djt[p]   = ok ? dinv(r, c) : 0.f;
        gofft[p] = ok ? (r * COLS + c) : -1;
    }

    // B-frag: MFMA column n of instance nt supplies feature f = n*4 + nt
    // (consecutive features per lane -> vectorizable epilogue writes).
    short8 bfrag[2][4];
    for (int kt = 0; kt < 2; ++kt)
        for (int nt = 0; nt < 4; ++nt)
            for (int j = 0; j < 8; ++j)
                bfrag[kt][nt][j] = (short)f2bf(W[(kt * 32 + q * 8 + j) * FDIM + (n * 4 + nt)]);
    __syncthreads();

    const float4 av4 = *(const float4*)&abv[n * 4];
    const float4 bv4 = *(const float4*)&abv[64 + n * 4];

    // Phase A: GEMM -> affine -> relu -> *d_j -> LDS (bf16, swizzled)
    for (int ch = wid; ch < NCHUNK; ch += 4) {
        const int p  = ch * 16 + n;
        const int go = gofft[p];
        short8 a0 = {}, a1 = {};
        if (USEHBF) {
            if (go >= 0) {
                const short8* ap = (const short8*)(hbf + base + (size_t)go * FDIM);
                a0 = ap[q];
                a1 = ap[q + 4];
            }
        } else {
            if (go >= 0) {
                const float4* apx = (const float4*)(H + base + (size_t)go * FDIM + q * 8);
                a0 = pack8(apx[0], apx[1]);
                a1 = pack8(apx[8], apx[9]);
            }
        }
        floatx4 acc[4] = {};
        #pragma unroll
        for (int nt = 0; nt < 4; ++nt) {
            acc[nt] = __builtin_amdgcn_mfma_f32_16x16x32_bf16(a0, bfrag[0][nt], acc[nt], 0, 0, 0);
            acc[nt] = __builtin_amdgcn_mfma_f32_16x16x32_bf16(a1, bfrag[1][nt], acc[nt], 0, 0, 0);
        }
        const int pb = ch * 16 + q * 4;
        const floatx4 dj4 = *(const floatx4*)&djt[pb];
        #pragma unroll
        for (int rr = 0; rr < 4; ++rr) {
            ushort4 w4;
            w4.x = f2bf(fmaxf(fmaf(acc[0][rr], av4.x, bv4.x), 0.f) * dj4[rr]);
            w4.y = f2bf(fmaxf(fmaf(acc[1][rr], av4.y, bv4.y), 0.f) * dj4[rr]);
            w4.z = f2bf(fmaxf(fmaf(acc[2][rr], av4.z, bv4.z), 0.f) * dj4[rr]);
            w4.w = f2bf(fmaxf(fmaf(acc[3][rr], av4.w, bv4.w), 0.f) * dj4[rr]);
            *(ushort4*)pswz(P, pb + rr, n * 8) = w4;   // OOB rows: dj=0 -> 0
        }
    }
    __syncthreads();

    // Phase B: separable 3x3 stencil via rolling column sums, * d_i, store
    {
        const int fg  = tid & 7;              // feature group (8 floats)
        const int ocg = (tid >> 3) & 3;       // 8-col strip
        const int orr = tid >> 5;             // output row 0..7
        const int hc0 = ocg * 8;              // first halo col of strip
        const int fb  = fg * 16;              // feature byte offset

        float cs[3][8];
        #pragma unroll
        for (int ini = 0; ini < 2; ++ini) {
            const short8 v0 = *(const short8*)pswz(P, (orr + 0) * IW + hc0 + ini, fb);
            const short8 v1 = *(const short8*)pswz(P, (orr + 1) * IW + hc0 + ini, fb);
            const short8 v2 = *(const short8*)pswz(P, (orr + 2) * IW + hc0 + ini, fb);
            #pragma unroll
            for (int j = 0; j < 8; ++j)
                cs[ini][j] = bf2f((unsigned short)v0[j]) + bf2f((unsigned short)v1[j])
                           + bf2f((unsigned short)v2[j]);
        }

        const int r = r0 + orr;
        float* orow = out + base + ((size_t)r * COLS + (c0 + hc0)) * FDIM + fg * 8;
        #pragma unroll
        for (int jj = 0; jj < 8; ++jj) {
            const int i0 = jj % 3, i1 = (jj + 1) % 3, i2 = (jj + 2) % 3;
            const short8 v0 = *(const short8*)pswz(P, (orr + 0) * IW + hc0 + jj + 2, fb);
            const short8 v1 = *(const short8*)pswz(P, (orr + 1) * IW + hc0 + jj + 2, fb);
            const short8 v2 = *(const short8*)pswz(P, (orr + 2) * IW + hc0 + jj + 2, fb);
            #pragma unroll
            for (int j = 0; j < 8; ++j)
                cs[i2][j] = bf2f((unsigned short)v0[j]) + bf2f((unsigned short)v1[j])
                          + bf2f((unsigned short)v2[j]);
            const float d = djt[(orr + 1) * IW + hc0 + jj + 1];
            float4 o0, o1;
            o0.x = (cs[i0][0] + cs[i1][0] + cs[i2][0]) * d;
            o0.y = (cs[i0][1] + cs[i1][1] + cs[i2][1]) * d;
            o0.z = (cs[i0][2] + cs[i1][2] + cs[i2][2]) * d;
            o0.w = (cs[i0][3] + cs[i1][3] + cs[i2][3]) * d;
            o1.x = (cs[i0][4] + cs[i1][4] + cs[i2][4]) * d;
            o1.y = (cs[i0][5] + cs[i1][5] + cs[i2][5]) * d;
            o1.z = (cs[i0][6] + cs[i1][6] + cs[i2][6]) * d;
            o1.w = (cs[i0][7] + cs[i1][7] + cs[i2][7]) * d;
            float4* op = (float4*)(orow + (size_t)jj * FDIM);
            op[0] = o0; op[1] = o1;
        }
    }
}

extern "C" void kernel_launch(void* const* d_in, const int* in_sizes, int n_in,
                              void* d_out, int out_size, void* d_ws, size_t ws_size,
                              hipStream_t stream) {
    const float* H     = (const float*)d_in[0];
    const float* W     = (const float*)d_in[1];
    const float* gamma = (const float*)d_in[2];
    const float* beta  = (const float*)d_in[3];
    float* out = (float*)d_out;

    float* ab       = (float*)d_ws;          // [128]
    float* stats    = ab + 128;              // [128]  (atomic fallback)
    float* partials = stats + 128;           // [128][NB1] (partials path)
    unsigned short* hbf = (unsigned short*)(partials + (size_t)128 * NB1);

    const size_t need_part = (size_t)(256 + 128 * NB1) * sizeof(float);
    const size_t need_full = need_part + (size_t)MTOT * FDIM * sizeof(unsigned short);

    if (ws_size >= need_full) {
        // bf16-H cached in ws: K3 skips fp32 loads + pack8 entirely
        k1_stats<<<NB1, 256, 0, stream>>>(H, W, partials, nullptr, hbf);
        k2_reduce<<<64, 256, 0, stream>>>(partials, gamma, beta, ab);
        k3_fused<1><<<BATCH * 32 * 8, 256, 0, stream>>>(H, hbf, W, ab, out);
    } else if (ws_size >= need_part) {
        k1_stats<<<NB1, 256, 0, stream>>>(H, W, partials, nullptr, nullptr);
        k2_reduce<<<64, 256, 0, stream>>>(partials, gamma, beta, ab);
        k3_fused<0><<<BATCH * 32 * 8, 256, 0, stream>>>(H, nullptr, W, ab, out);
    } else {
        hipMemsetAsync(stats, 0, 128 * sizeof(float), stream);
        k1_stats<<<NB1, 256, 0, stream>>>(H, W, nullptr, stats, nullptr);
        k2_finalize<<<1, 64, 0, stream>>>(stats, gamma, beta, ab);
        k3_fused<0><<<BATCH * 32 * 8, 256, 0, stream>>>(H, nullptr, W, ab, out);
    }
}